// Round 1
// baseline (6777.787 us; speedup 1.0000x reference)
//
#include <hip/hip_runtime.h>
#include <hip/hip_bf16.h>

// Problem constants: B=8, T=512, V=32000, E=256, H=512
typedef __attribute__((ext_vector_type(8))) short short8;
typedef __attribute__((ext_vector_type(4))) float f32x4;

__device__ __forceinline__ void glds16(const void* g, void* l) {
  __builtin_amdgcn_global_load_lds(
      (const __attribute__((address_space(1))) unsigned int*)g,
      (__attribute__((address_space(3))) unsigned int*)l, 16, 0, 0);
}

__device__ __forceinline__ float fast_tanh(float x) {
  // |x| < 40 guaranteed by operand bounds (|q|,|k| <= ~19). exp-based, rcp approx.
  float e = __expf(2.0f * x);
  return (e - 1.0f) * __builtin_amdgcn_rcpf(e + 1.0f);
}

__device__ __forceinline__ short bf16r(float f) {
  __hip_bfloat16 h = __float2bfloat16(f);
  return *reinterpret_cast<short*>(&h);
}

// ---------------------------------------------------------------- K0: fp32 -> bf16 bulk convert
__global__ __launch_bounds__(256) void k_cvt_bf16(const float* __restrict__ src,
                                                  unsigned short* __restrict__ dst, int n) {
  int i = (blockIdx.x * 256 + threadIdx.x) * 8;
  if (i >= n) return;
  float4 a = *(const float4*)(src + i);
  float4 b = *(const float4*)(src + i + 4);
  short8 v;
  v[0] = bf16r(a.x); v[1] = bf16r(a.y); v[2] = bf16r(a.z); v[3] = bf16r(a.w);
  v[4] = bf16r(b.x); v[5] = bf16r(b.y); v[6] = bf16r(b.z); v[7] = bf16r(b.w);
  *(short8*)(dst + i) = v;
}

// ---------------------------------------------------------------- K1: xin = emb(x) @ W_ih^T + b_ih
// grid (64 bt-tiles, 8 j-tiles), block 256. A-tile natural [64][128], B-tile transposed [128][64].
__global__ __launch_bounds__(256) void k_xin(const int* __restrict__ x, const float* __restrict__ embed,
                                             const float* __restrict__ W_ih, const float* __restrict__ b_ih,
                                             float* __restrict__ xin) {
  __shared__ float At[64][128];
  __shared__ float Bt[128][64];
  const int tid = threadIdx.x;
  const int bt0 = blockIdx.x * 64, j0 = blockIdx.y * 64;
  const int ty = tid >> 4, tx = tid & 15;
  const int lane = tid & 63, cgrp = tid >> 6;
  float acc[4][4] = {};
  for (int kc = 0; kc < 256; kc += 128) {
#pragma unroll
    for (int rr = 0; rr < 8; ++rr) {
      int row = rr * 8 + (tid >> 5);
      int col = (tid & 31) * 4;
      int tok = x[bt0 + row];
      float4 v = make_float4(0.f, 0.f, 0.f, 0.f);
      if (tok != 0) v = *(const float4*)&embed[(size_t)tok * 256 + kc + col];
      *(float4*)&At[row][col] = v;
    }
#pragma unroll
    for (int cc = 0; cc < 8; ++cc) {
      int col = cgrp * 32 + cc * 4;
      float4 v = *(const float4*)&W_ih[(size_t)(j0 + lane) * 256 + kc + col];
      Bt[col + 0][lane] = v.x; Bt[col + 1][lane] = v.y;
      Bt[col + 2][lane] = v.z; Bt[col + 3][lane] = v.w;
    }
    __syncthreads();
    for (int kk = 0; kk < 128; ++kk) {
      float bv[4];
#pragma unroll
      for (int c = 0; c < 4; ++c) bv[c] = Bt[kk][tx * 4 + c];
#pragma unroll
      for (int a = 0; a < 4; ++a) {
        float av = At[ty * 4 + a][kk];
#pragma unroll
        for (int c = 0; c < 4; ++c) acc[a][c] = fmaf(av, bv[c], acc[a][c]);
      }
    }
    __syncthreads();
  }
#pragma unroll
  for (int a = 0; a < 4; ++a) {
    int m = bt0 + ty * 4 + a;
#pragma unroll
    for (int c = 0; c < 4; ++c) {
      int j = j0 + tx * 4 + c;
      xin[(size_t)m * 512 + j] = acc[a][c] + b_ih[j];
    }
  }
}

// ---------------------------------------------------------------- K2: persistent RNN scan
// 8 blocks x 1024 thr. Block k owns W_hh rows [64k,64k+64) in registers (float2 x16/thread).
// Per step: LDS-broadcast h, 16-lane dot-reduce, tanh, publish slice, device-scope flag barrier.
__global__ __launch_bounds__(1024) void k_rnn(const float* __restrict__ xin, const float* __restrict__ W_hh,
                                              const float* __restrict__ b_hh, const int* __restrict__ lengths,
                                              float* __restrict__ hglob, int* flags, float* __restrict__ out) {
  const int blk = blockIdx.x, tid = threadIdx.x;
  const int jl = tid >> 4, p = tid & 15;
  const int j = blk * 64 + jl;
  __shared__ float hbuf[8][512];
  // W columns rotated by p so LDS reads are staggered across banks (conflict-free)
  float2 w2[16];
#pragma unroll
  for (int i = 0; i < 16; ++i) {
    int c = ((i + p) & 15) * 2;
    w2[i] = *(const float2*)&W_hh[(size_t)j * 512 + p * 32 + c];
  }
  const float bj = b_hh[j];
  int len[8];
#pragma unroll
  for (int b = 0; b < 8; ++b) len[b] = lengths[b];
  for (int i = tid; i < 8 * 512; i += 1024) ((float*)hbuf)[i] = 0.f;
  __syncthreads();

  for (int t = 0; t < 512; ++t) {
    float xv[8];
    if (p == 0) {
#pragma unroll
      for (int b = 0; b < 8; ++b) xv[b] = xin[((size_t)b * 512 + t) * 512 + j];
    }
    float part[8];
#pragma unroll
    for (int b = 0; b < 8; ++b) {
      const float* hb = &hbuf[b][p * 32];
      float2 a2 = make_float2(0.f, 0.f);
#pragma unroll
      for (int i = 0; i < 16; ++i) {
        int c = ((i + p) & 15) * 2;
        float2 hv = *(const float2*)(hb + c);
        a2.x = fmaf(w2[i].x, hv.x, a2.x);
        a2.y = fmaf(w2[i].y, hv.y, a2.y);
      }
      part[b] = a2.x + a2.y;
    }
#pragma unroll
    for (int b = 0; b < 8; ++b) {
      float v = part[b];
      v += __shfl_xor(v, 1); v += __shfl_xor(v, 2);
      v += __shfl_xor(v, 4); v += __shfl_xor(v, 8);
      part[b] = v;
    }
    const int nxt = (t + 1) & 1;
    if (p == 0) {
#pragma unroll
      for (int b = 0; b < 8; ++b) {
        float hn = tanhf(xv[b] + part[b] + bj);
        hglob[(size_t)nxt * 4096 + (size_t)b * 512 + j] = hn;
        out[((size_t)b * 512 + t) * 512 + j] = (t < len[b]) ? hn : 0.f;
      }
      __threadfence();  // make h slice device-visible before flag
    }
    __syncthreads();
    if (tid == 0)
      __hip_atomic_store(&flags[blk], t + 1, __ATOMIC_RELEASE, __HIP_MEMORY_SCOPE_AGENT);
    if (t == 511) break;
    if (tid < 8) {
      while (__hip_atomic_load(&flags[tid], __ATOMIC_ACQUIRE, __HIP_MEMORY_SCOPE_AGENT) < t + 1) {
        __builtin_amdgcn_s_sleep(1);
      }
    }
    __syncthreads();
#pragma unroll
    for (int i = 0; i < 4; ++i) {
      int idx = i * 1024 + tid;
      ((float*)hbuf)[idx] = __hip_atomic_load(&hglob[(size_t)nxt * 4096 + idx],
                                              __ATOMIC_RELAXED, __HIP_MEMORY_SCOPE_AGENT);
    }
    __syncthreads();
  }
}

// ---------------------------------------------------------------- K3: q = out@W1^T ; k^T = out@W2^T + b (MODE 1 stores transposed [b][j][t])
template <int MODE>
__global__ __launch_bounds__(256) void k_qk(const float* __restrict__ out, const float* __restrict__ attn_W,
                                            const float* __restrict__ attn_b, float* __restrict__ dst) {
  __shared__ float At[64][128];
  __shared__ float Bt[128][64];
  const int tid = threadIdx.x;
  const int bt0 = blockIdx.x * 64, j0 = blockIdx.y * 64;
  const int ty = tid >> 4, tx = tid & 15;
  const int lane = tid & 63, cgrp = tid >> 6;
  float acc[4][4] = {};
  for (int kc = 0; kc < 512; kc += 128) {
#pragma unroll
    for (int rr = 0; rr < 8; ++rr) {
      int row = rr * 8 + (tid >> 5);
      int col = (tid & 31) * 4;
      *(float4*)&At[row][col] = *(const float4*)&out[((size_t)bt0 + row) * 512 + kc + col];
    }
#pragma unroll
    for (int cc = 0; cc < 8; ++cc) {
      int col = cgrp * 32 + cc * 4;
      float4 v = *(const float4*)&attn_W[(size_t)(j0 + lane) * 1024 + (MODE ? 512 : 0) + kc + col];
      Bt[col + 0][lane] = v.x; Bt[col + 1][lane] = v.y;
      Bt[col + 2][lane] = v.z; Bt[col + 3][lane] = v.w;
    }
    __syncthreads();
    for (int kk = 0; kk < 128; ++kk) {
      float bv[4];
#pragma unroll
      for (int c = 0; c < 4; ++c) bv[c] = Bt[kk][tx * 4 + c];
#pragma unroll
      for (int a = 0; a < 4; ++a) {
        float av = At[ty * 4 + a][kk];
#pragma unroll
        for (int c = 0; c < 4; ++c) acc[a][c] = fmaf(av, bv[c], acc[a][c]);
      }
    }
    __syncthreads();
  }
#pragma unroll
  for (int a = 0; a < 4; ++a) {
    int bt = bt0 + ty * 4 + a;
#pragma unroll
    for (int c = 0; c < 4; ++c) {
      int j = j0 + tx * 4 + c;
      if (MODE == 0) {
        dst[(size_t)bt * 512 + j] = acc[a][c];
      } else {
        int bb = bt >> 9, tt = bt & 511;
        dst[((size_t)bb * 512 + j) * 512 + tt] = acc[a][c] + attn_b[j];
      }
    }
  }
}

// ---------------------------------------------------------------- K4: p[b][t][s] = exp(score-20) masked
// grid (8 b, 128 t-tiles of 4), block 256. Fixed-shift softmax numerator (scores bounded).
__global__ __launch_bounds__(256) void k_scores(const float* __restrict__ q, const float* __restrict__ kT,
                                                const float* __restrict__ attn_v, const float* __restrict__ attn_v_b,
                                                const int* __restrict__ lengths, float* __restrict__ pbuf) {
  const int b = blockIdx.x, t0 = blockIdx.y * 4;
  const int tid = threadIdx.x;
  __shared__ float qL[4][512];
  __shared__ float vL[512];
  for (int i = tid; i < 4 * 512; i += 256) {
    int r = i >> 9, h = i & 511;
    qL[r][h] = q[((size_t)b * 512 + t0 + r) * 512 + h];
  }
  for (int i = tid; i < 512; i += 256) vL[i] = attn_v[i];
  const float vb = attn_v_b[0];
  const int len = lengths[b];
  __syncthreads();
  const int s_hi = min(t0 + 3, len - 1);
  const float* kTb = kT + (size_t)b * 512 * 512;
#pragma unroll
  for (int si = 0; si < 2; ++si) {
    int s = tid + si * 256;
    float acc[4] = {0.f, 0.f, 0.f, 0.f};
    if (s <= s_hi) {
      for (int h = 0; h < 512; ++h) {
        float kv = kTb[(size_t)h * 512 + s];
        float vh = vL[h];
#pragma unroll
        for (int r = 0; r < 4; ++r) acc[r] = fmaf(vh, fast_tanh(qL[r][h] + kv), acc[r]);
      }
    }
#pragma unroll
    for (int r = 0; r < 4; ++r) {
      int t = t0 + r;
      bool valid = (s <= t) && (s < len);
      pbuf[((size_t)b * 512 + t) * 512 + s] = valid ? __expf(acc[r] + vb - 20.f) : 0.f;
    }
  }
}

// ---------------------------------------------------------------- K5: invl[row] = 1 / sum_s p[row][s]
__global__ __launch_bounds__(256) void k_rowinv(const float* __restrict__ pbuf, float* __restrict__ invl) {
  int row = blockIdx.x * 4 + (threadIdx.x >> 6);
  int lane = threadIdx.x & 63;
  const float* pr = pbuf + (size_t)row * 512;
  float s = 0.f;
#pragma unroll
  for (int i = 0; i < 8; ++i) s += pr[lane + i * 64];
#pragma unroll
  for (int m = 1; m < 64; m <<= 1) s += __shfl_xor(s, m);
  if (lane == 0) invl[row] = 1.0f / s;
}

// ---------------------------------------------------------------- K5b: feats[:, 0:512] = bf16(out)
__global__ __launch_bounds__(256) void k_cvt_out_feats(const float* __restrict__ out,
                                                       unsigned short* __restrict__ feats) {
  int i = (blockIdx.x * 256 + threadIdx.x) * 8;  // over 4096*512
  int m = i >> 9, c = i & 511;
  float4 a = *(const float4*)(out + i);
  float4 b = *(const float4*)(out + i + 4);
  short8 v;
  v[0] = bf16r(a.x); v[1] = bf16r(a.y); v[2] = bf16r(a.z); v[3] = bf16r(a.w);
  v[4] = bf16r(b.x); v[5] = bf16r(b.y); v[6] = bf16r(b.z); v[7] = bf16r(b.w);
  *(short8*)(feats + (size_t)m * 1024 + c) = v;
}

// ---------------------------------------------------------------- K6: feats[:, 512:1024] = bf16((p @ out) * invl)
// grid (8 h-tiles, 8 t-tiles, 8 b), block 256.
__global__ __launch_bounds__(256) void k_context(const float* __restrict__ pbuf, const float* __restrict__ out,
                                                 const float* __restrict__ invl, unsigned short* __restrict__ feats) {
  __shared__ float Pt[64][128];
  __shared__ float Ot[128][64];
  const int b = blockIdx.z, t0 = blockIdx.y * 64, h0 = blockIdx.x * 64;
  const int tid = threadIdx.x, ty = tid >> 4, tx = tid & 15;
  float acc[4][4] = {};
  for (int sc = 0; sc < 512; sc += 128) {
#pragma unroll
    for (int rr = 0; rr < 8; ++rr) {
      int row = rr * 8 + (tid >> 5);
      int col = (tid & 31) * 4;
      *(float4*)&Pt[row][col] = *(const float4*)&pbuf[((size_t)b * 512 + t0 + row) * 512 + sc + col];
    }
#pragma unroll
    for (int rr = 0; rr < 8; ++rr) {
      int srow = rr * 16 + (tid >> 4);
      int col = (tid & 15) * 4;
      *(float4*)&Ot[srow][col] = *(const float4*)&out[((size_t)b * 512 + sc + srow) * 512 + h0 + col];
    }
    __syncthreads();
    for (int kk = 0; kk < 128; ++kk) {
      float ov[4];
#pragma unroll
      for (int c = 0; c < 4; ++c) ov[c] = Ot[kk][tx * 4 + c];
#pragma unroll
      for (int a = 0; a < 4; ++a) {
        float pv = Pt[ty * 4 + a][kk];
#pragma unroll
        for (int c = 0; c < 4; ++c) acc[a][c] = fmaf(pv, ov[c], acc[a][c]);
      }
    }
    __syncthreads();
  }
#pragma unroll
  for (int a = 0; a < 4; ++a) {
    int t = t0 + ty * 4 + a;
    float il = invl[b * 512 + t];
#pragma unroll
    for (int c = 0; c < 4; ++c) {
      int h = h0 + tx * 4 + c;
      feats[((size_t)b * 512 + t) * 1024 + 512 + h] = (unsigned short)bf16r(acc[a][c] * il);
    }
  }
}

// ---------------------------------------------------------------- K7: logits = feats @ fc_W^T + fc_b  (bf16 MFMA, m97-style 128x128)
__global__ __launch_bounds__(256) void k_logits(const unsigned short* __restrict__ A,
                                                const unsigned short* __restrict__ Bw,
                                                const float* __restrict__ bias, float* __restrict__ C) {
  __shared__ unsigned short As[128 * 64];  // [m][k], row stride 64 (128B)
  __shared__ unsigned short Bs[128 * 64];  // [n][k]
  const int tid = threadIdx.x;
  const int wave = tid >> 6, lane = tid & 63;
  const int m0 = blockIdx.x * 128, n0 = blockIdx.y * 128;
  const int wm = (wave >> 1) * 64, wn = (wave & 1) * 64;
  const int lo16 = lane & 15, oct = lane >> 4;
  f32x4 acc[4][4] = {};
  for (int kt = 0; kt < 1024; kt += 64) {
#pragma unroll
    for (int i = 0; i < 4; ++i) {
      int ci = wave * 4 + i;               // 16 chunks of 1KB per tile
      int mrow = ci * 8 + (lane >> 3);     // 0..127
      int k8 = (lane & 7) * 8;
      glds16(&A[(size_t)(m0 + mrow) * 1024 + kt + k8], &As[ci * 512]);
      glds16(&Bw[(size_t)(n0 + mrow) * 1024 + kt + k8], &Bs[ci * 512]);
    }
    __syncthreads();
#pragma unroll
    for (int kk = 0; kk < 2; ++kk) {
      short8 af[4], bf[4];
#pragma unroll
      for (int i = 0; i < 4; ++i)
        af[i] = *(const short8*)&As[(wm + i * 16 + lo16) * 64 + kk * 32 + oct * 8];
#pragma unroll
      for (int jn = 0; jn < 4; ++jn)
        bf[jn] = *(const short8*)&Bs[(wn + jn * 16 + lo16) * 64 + kk * 32 + oct * 8];
#pragma unroll
      for (int i = 0; i < 4; ++i)
#pragma unroll
        for (int jn = 0; jn < 4; ++jn)
          acc[i][jn] = __builtin_amdgcn_mfma_f32_16x16x32_bf16(af[i], bf[jn], acc[i][jn], 0, 0, 0);
    }
    __syncthreads();
  }
#pragma unroll
  for (int jn = 0; jn < 4; ++jn) {
    int n = n0 + wn + jn * 16 + lo16;
    float bv = bias[n];
#pragma unroll
    for (int i = 0; i < 4; ++i) {
      int mbase = m0 + wm + i * 16 + oct * 4;
#pragma unroll
      for (int r = 0; r < 4; ++r)
        C[(size_t)(mbase + r) * 32000 + n] = acc[i][jn][r] + bv;
    }
  }
}

// ---------------------------------------------------------------- launch
extern "C" void kernel_launch(void* const* d_in, const int* in_sizes, int n_in,
                              void* d_out, int out_size, void* d_ws, size_t ws_size,
                              hipStream_t stream) {
  const int* x = (const int*)d_in[0];
  const int* lengths = (const int*)d_in[1];
  const float* embed = (const float*)d_in[2];
  const float* W_ih = (const float*)d_in[3];
  const float* W_hh = (const float*)d_in[4];
  const float* b_ih = (const float*)d_in[5];
  const float* b_hh = (const float*)d_in[6];
  const float* attn_W = (const float*)d_in[7];
  const float* attn_b = (const float*)d_in[8];
  const float* attn_v = (const float*)d_in[9];
  const float* attn_v_b = (const float*)d_in[10];
  const float* fc_W = (const float*)d_in[11];
  const float* fc_b = (const float*)d_in[12];
  float* logits = (float*)d_out;

  char* ws = (char*)d_ws;
  const size_t MB8 = 8388608;
  float* xin  = (float*)(ws);                         // 8 MB  [b][t][h]
  float* outp = (float*)(ws + 1 * MB8);               // 8 MB  masked RNN outputs
  float* q    = (float*)(ws + 2 * MB8);               // 8 MB
  float* kT   = (float*)(ws + 3 * MB8);               // 8 MB  [b][h][s]
  float* pbuf = (float*)(ws + 4 * MB8);               // 8 MB  [b][t][s]
  float* invl = (float*)(ws + 5 * MB8);               // 16 KB
  unsigned short* feats = (unsigned short*)(ws + 5 * MB8 + 16384);        // 8 MB  [bt][1024] bf16
  unsigned short* fcWb  = (unsigned short*)(ws + 6 * MB8 + 16384);        // 64 MB bf16
  float* hglob = (float*)(ws + 6 * MB8 + 16384 + 65536000);               // 32 KB [2][8][512]
  int* flags   = (int*)(ws + 6 * MB8 + 16384 + 65536000 + 32768);         // 256 B

  hipMemsetAsync(flags, 0, 256, stream);
  k_cvt_bf16<<<16000, 256, 0, stream>>>(fc_W, fcWb, 32768000);
  k_xin<<<dim3(64, 8), 256, 0, stream>>>(x, embed, W_ih, b_ih, xin);
  k_rnn<<<8, 1024, 0, stream>>>(xin, W_hh, b_hh, lengths, hglob, flags, outp);
  k_qk<0><<<dim3(64, 8), 256, 0, stream>>>(outp, attn_W, attn_b, q);
  k_qk<1><<<dim3(64, 8), 256, 0, stream>>>(outp, attn_W, attn_b, kT);
  k_scores<<<dim3(8, 128), 256, 0, stream>>>(q, kT, attn_v, attn_v_b, lengths, pbuf);
  k_rowinv<<<1024, 256, 0, stream>>>(pbuf, invl);
  k_cvt_out_feats<<<1024, 256, 0, stream>>>(outp, feats);
  k_context<<<dim3(8, 8, 8), 256, 0, stream>>>(pbuf, outp, invl, feats);
  k_logits<<<dim3(32, 250), 256, 0, stream>>>(feats, fcWb, fc_b, logits);
}

// Round 2
// 5242.054 us; speedup vs baseline: 1.2930x; 1.2930x over previous
//
#include <hip/hip_runtime.h>
#include <hip/hip_bf16.h>

// Problem constants: B=8, T=512, V=32000, E=256, H=512
typedef __attribute__((ext_vector_type(8))) short short8;
typedef __attribute__((ext_vector_type(4))) float f32x4;

#define AL(p)    __hip_atomic_load((p), __ATOMIC_RELAXED, __HIP_MEMORY_SCOPE_AGENT)
#define AS(p, v) __hip_atomic_store((p), (v), __ATOMIC_RELAXED, __HIP_MEMORY_SCOPE_AGENT)

__device__ __forceinline__ void glds16(const void* g, void* l) {
  __builtin_amdgcn_global_load_lds(
      (const __attribute__((address_space(1))) unsigned int*)g,
      (__attribute__((address_space(3))) unsigned int*)l, 16, 0, 0);
}

__device__ __forceinline__ float fast_tanh(float x) {
  float e = __expf(2.0f * x);
  return (e - 1.0f) * __builtin_amdgcn_rcpf(e + 1.0f);
}

__device__ __forceinline__ unsigned short bfh(float f) {
  __hip_bfloat16 h = __float2bfloat16(f);
  return *reinterpret_cast<unsigned short*>(&h);
}
__device__ __forceinline__ float bf2f(unsigned short u) {
  unsigned v = ((unsigned)u) << 16;
  float f;
  __builtin_memcpy(&f, &v, 4);
  return f;
}
__device__ __forceinline__ short bf16r(float f) { return (short)bfh(f); }

union FragU {
  unsigned int u[4];
  short8 s;
};

// ---------------------------------------------------------------- K0: fp32 -> bf16 bulk convert
__global__ __launch_bounds__(256) void k_cvt_bf16(const float* __restrict__ src,
                                                  unsigned short* __restrict__ dst, int n) {
  int i = (blockIdx.x * 256 + threadIdx.x) * 8;
  if (i >= n) return;
  float4 a = *(const float4*)(src + i);
  float4 b = *(const float4*)(src + i + 4);
  short8 v;
  v[0] = bf16r(a.x); v[1] = bf16r(a.y); v[2] = bf16r(a.z); v[3] = bf16r(a.w);
  v[4] = bf16r(b.x); v[5] = bf16r(b.y); v[6] = bf16r(b.z); v[7] = bf16r(b.w);
  *(short8*)(dst + i) = v;
}

// ---------------------------------------------------------------- K1: xin = emb(x) @ W_ih^T + b_ih
__global__ __launch_bounds__(256) void k_xin(const int* __restrict__ x, const float* __restrict__ embed,
                                             const float* __restrict__ W_ih, const float* __restrict__ b_ih,
                                             float* __restrict__ xin) {
  __shared__ float At[64][128];
  __shared__ float Bt[128][64];
  const int tid = threadIdx.x;
  const int bt0 = blockIdx.x * 64, j0 = blockIdx.y * 64;
  const int ty = tid >> 4, tx = tid & 15;
  const int lane = tid & 63, cgrp = tid >> 6;
  float acc[4][4] = {};
  for (int kc = 0; kc < 256; kc += 128) {
#pragma unroll
    for (int rr = 0; rr < 8; ++rr) {
      int row = rr * 8 + (tid >> 5);
      int col = (tid & 31) * 4;
      int tok = x[bt0 + row];
      float4 v = make_float4(0.f, 0.f, 0.f, 0.f);
      if (tok != 0) v = *(const float4*)&embed[(size_t)tok * 256 + kc + col];
      *(float4*)&At[row][col] = v;
    }
#pragma unroll
    for (int cc = 0; cc < 8; ++cc) {
      int col = cgrp * 32 + cc * 4;
      float4 v = *(const float4*)&W_ih[(size_t)(j0 + lane) * 256 + kc + col];
      Bt[col + 0][lane] = v.x; Bt[col + 1][lane] = v.y;
      Bt[col + 2][lane] = v.z; Bt[col + 3][lane] = v.w;
    }
    __syncthreads();
    for (int kk = 0; kk < 128; ++kk) {
      float bv[4];
#pragma unroll
      for (int c = 0; c < 4; ++c) bv[c] = Bt[kk][tx * 4 + c];
#pragma unroll
      for (int a = 0; a < 4; ++a) {
        float av = At[ty * 4 + a][kk];
#pragma unroll
        for (int c = 0; c < 4; ++c) acc[a][c] = fmaf(av, bv[c], acc[a][c]);
      }
    }
    __syncthreads();
  }
#pragma unroll
  for (int a = 0; a < 4; ++a) {
    int m = bt0 + ty * 4 + a;
#pragma unroll
    for (int c = 0; c < 4; ++c) {
      int j = j0 + tx * 4 + c;
      xin[(size_t)m * 512 + j] = acc[a][c] + b_ih[j];
    }
  }
}

// ---------------------------------------------------------------- K2: persistent RNN scan (split-bf16 MFMA + LLC relaxed-atomic sync)
// 8 blocks x 512 thr (8 waves). Block owns j-window [64*blk, 64*blk+64).
// Wave w: j-tile = w&3 (16 j), K-half = w>>2 (8 chunks of K=32).
// h exchanged via LLC as packed bf16 hi/lo pairs; W_hh pre-split into register
// bf16 hi/lo fragments. 3-term split MFMA (hi*hi + hi*lo + lo*hi), err ~2^-16.
__global__ __launch_bounds__(512) void k_rnn(const float* __restrict__ xin, const float* __restrict__ W_hh,
                                             const float* __restrict__ b_hh, const int* __restrict__ lengths,
                                             unsigned int* hhi32, unsigned int* hlo32, int* flags,
                                             float* __restrict__ out) {
  const int blk = blockIdx.x, tid = threadIdx.x;
  const int w = tid >> 6, l = tid & 63;
  const int jt = w & 3, kh = w >> 2;
  const int j16 = blk * 64 + jt * 16;
  const int r = l & 15;       // A row (=batch b) / B col (=j within tile)
  const int g = l >> 4;       // k-group
  const int n = l & 15;

  __shared__ f32x4 Cbuf[4][64];
  __shared__ float hL[8][64];

  // ---- preload W fragments (bf16 hi/lo), 8 chunks per wave
  short8 bhi[8], blo[8];
  {
    const float* wrow = &W_hh[(size_t)(j16 + n) * 512];
#pragma unroll
    for (int c8 = 0; c8 < 8; ++c8) {
      int c = kh * 8 + c8;
      const float* wp = wrow + c * 32 + g * 8;
      float4 wa = *(const float4*)wp;
      float4 wb = *(const float4*)(wp + 4);
      float wv[8] = {wa.x, wa.y, wa.z, wa.w, wb.x, wb.y, wb.z, wb.w};
#pragma unroll
      for (int e = 0; e < 8; ++e) {
        unsigned short h = bfh(wv[e]);
        bhi[c8][e] = (short)h;
        blo[c8][e] = (short)bfh(wv[e] - bf2f(h));
      }
    }
  }

  // ---- per-lane epilogue constants (waves 0..3, lanes 0..31)
  float bj = 0.f, xv[4];
  int len4[4];
  if (w < 4 && l < 32) {
    bj = b_hh[j16 + n];
#pragma unroll
    for (int i = 0; i < 4; ++i) {
      int b = g * 4 + i;
      len4[i] = lengths[b];
      xv[i] = xin[((size_t)b * 512 + 0) * 512 + j16 + n];  // t=0
    }
  }

  for (int t = 0; t < 512; ++t) {
    // ---- wait for all producers to publish h_t
    if (l < 8) {
      while (AL(&flags[l]) < t) { }
    }
    asm volatile("" ::: "memory");

    // ---- A fragments from LLC (packed bf16 hi/lo), MFMA accumulate
    const unsigned int* hb = hhi32 + (t & 1) * 2048;
    const unsigned int* lb = hlo32 + (t & 1) * 2048;
    f32x4 acc0 = {}, acc1 = {};
#pragma unroll
    for (int c8 = 0; c8 < 8; ++c8) {
      int c = kh * 8 + c8;
      int bi = r * 256 + c * 16 + g * 4;
      FragU ah, al;
      if (r < 8) {
        ah.u[0] = AL(hb + bi); ah.u[1] = AL(hb + bi + 1);
        ah.u[2] = AL(hb + bi + 2); ah.u[3] = AL(hb + bi + 3);
        al.u[0] = AL(lb + bi); al.u[1] = AL(lb + bi + 1);
        al.u[2] = AL(lb + bi + 2); al.u[3] = AL(lb + bi + 3);
      } else {
        ah.u[0] = ah.u[1] = ah.u[2] = ah.u[3] = 0u;
        al.u[0] = al.u[1] = al.u[2] = al.u[3] = 0u;
      }
      if (c8 & 1) {
        acc1 = __builtin_amdgcn_mfma_f32_16x16x32_bf16(ah.s, bhi[c8], acc1, 0, 0, 0);
        acc1 = __builtin_amdgcn_mfma_f32_16x16x32_bf16(ah.s, blo[c8], acc1, 0, 0, 0);
        acc1 = __builtin_amdgcn_mfma_f32_16x16x32_bf16(al.s, bhi[c8], acc1, 0, 0, 0);
      } else {
        acc0 = __builtin_amdgcn_mfma_f32_16x16x32_bf16(ah.s, bhi[c8], acc0, 0, 0, 0);
        acc0 = __builtin_amdgcn_mfma_f32_16x16x32_bf16(ah.s, blo[c8], acc0, 0, 0, 0);
        acc0 = __builtin_amdgcn_mfma_f32_16x16x32_bf16(al.s, bhi[c8], acc0, 0, 0, 0);
      }
    }
    f32x4 tot = acc0 + acc1;

    // ---- cross-K-half reduce via LDS
    if (w >= 4) Cbuf[w - 4][l] = tot;
    __syncthreads();  // B1

    if (w < 4) {
      f32x4 oth = Cbuf[w][l];
      tot += oth;
      if (l < 32) {
#pragma unroll
        for (int i = 0; i < 4; ++i) {
          int b = g * 4 + i;
          float hn = fast_tanh(xv[i] + tot[i] + bj);
          out[((size_t)b * 512 + t) * 512 + j16 + n] = (t < len4[i]) ? hn : 0.f;
          hL[b][jt * 16 + n] = hn;
        }
        // prefetch xin for next step (latency hidden under next iteration)
        int tt = (t < 511) ? t + 1 : 511;
#pragma unroll
        for (int i = 0; i < 4; ++i)
          xv[i] = xin[((size_t)(g * 4 + i) * 512 + tt) * 512 + j16 + n];
      }
    }
    __syncthreads();  // B2: hL complete

    if (t < 511) {
      // ---- pack h_{t+1} window to bf16 hi/lo, publish to LLC (waves 4..7)
      if (tid >= 256) {
        int ii = tid - 256, b = ii >> 5, jp = ii & 31;
        float v0 = hL[b][jp * 2], v1 = hL[b][jp * 2 + 1];
        unsigned h0 = bfh(v0), h1 = bfh(v1);
        unsigned lo0 = bfh(v0 - bf2f((unsigned short)h0));
        unsigned lo1 = bfh(v1 - bf2f((unsigned short)h1));
        unsigned int* hw = hhi32 + ((t + 1) & 1) * 2048;
        unsigned int* lw = hlo32 + ((t + 1) & 1) * 2048;
        AS(hw + b * 256 + blk * 32 + jp, h0 | (h1 << 16));
        AS(lw + b * 256 + blk * 32 + jp, lo0 | (lo1 << 16));
      }
      __syncthreads();  // B3: drains vmcnt -> stores are at the coherence point
      if (tid == 0) AS(&flags[blk], t + 1);
    }
  }
}

// ---------------------------------------------------------------- K3: q = out@W1^T ; kT = out@W2^T + b
template <int MODE>
__global__ __launch_bounds__(256) void k_qk(const float* __restrict__ out, const float* __restrict__ attn_W,
                                            const float* __restrict__ attn_b, float* __restrict__ dst) {
  __shared__ float At[64][128];
  __shared__ float Bt[128][64];
  const int tid = threadIdx.x;
  const int bt0 = blockIdx.x * 64, j0 = blockIdx.y * 64;
  const int ty = tid >> 4, tx = tid & 15;
  const int lane = tid & 63, cgrp = tid >> 6;
  float acc[4][4] = {};
  for (int kc = 0; kc < 512; kc += 128) {
#pragma unroll
    for (int rr = 0; rr < 8; ++rr) {
      int row = rr * 8 + (tid >> 5);
      int col = (tid & 31) * 4;
      *(float4*)&At[row][col] = *(const float4*)&out[((size_t)bt0 + row) * 512 + kc + col];
    }
#pragma unroll
    for (int cc = 0; cc < 8; ++cc) {
      int col = cgrp * 32 + cc * 4;
      float4 v = *(const float4*)&attn_W[(size_t)(j0 + lane) * 1024 + (MODE ? 512 : 0) + kc + col];
      Bt[col + 0][lane] = v.x; Bt[col + 1][lane] = v.y;
      Bt[col + 2][lane] = v.z; Bt[col + 3][lane] = v.w;
    }
    __syncthreads();
    for (int kk = 0; kk < 128; ++kk) {
      float bv[4];
#pragma unroll
      for (int c = 0; c < 4; ++c) bv[c] = Bt[kk][tx * 4 + c];
#pragma unroll
      for (int a = 0; a < 4; ++a) {
        float av = At[ty * 4 + a][kk];
#pragma unroll
        for (int c = 0; c < 4; ++c) acc[a][c] = fmaf(av, bv[c], acc[a][c]);
      }
    }
    __syncthreads();
  }
#pragma unroll
  for (int a = 0; a < 4; ++a) {
    int bt = bt0 + ty * 4 + a;
#pragma unroll
    for (int c = 0; c < 4; ++c) {
      int j = j0 + tx * 4 + c;
      if (MODE == 0) {
        dst[(size_t)bt * 512 + j] = acc[a][c];
      } else {
        int bb = bt >> 9, tt = bt & 511;
        dst[((size_t)bb * 512 + j) * 512 + tt] = acc[a][c] + attn_b[j];
      }
    }
  }
}

// ---------------------------------------------------------------- K4: p[b][t][s] = exp(score-20) masked
__global__ __launch_bounds__(256) void k_scores(const float* __restrict__ q, const float* __restrict__ kT,
                                                const float* __restrict__ attn_v, const float* __restrict__ attn_v_b,
                                                const int* __restrict__ lengths, float* __restrict__ pbuf) {
  const int b = blockIdx.x, t0 = blockIdx.y * 4;
  const int tid = threadIdx.x;
  __shared__ float qL[4][512];
  __shared__ float vL[512];
  for (int i = tid; i < 4 * 512; i += 256) {
    int rr = i >> 9, h = i & 511;
    qL[rr][h] = q[((size_t)b * 512 + t0 + rr) * 512 + h];
  }
  for (int i = tid; i < 512; i += 256) vL[i] = attn_v[i];
  const float vb = attn_v_b[0];
  const int len = lengths[b];
  __syncthreads();
  const int s_hi = min(t0 + 3, len - 1);
  const float* kTb = kT + (size_t)b * 512 * 512;
#pragma unroll
  for (int si = 0; si < 2; ++si) {
    int s = tid + si * 256;
    float acc[4] = {0.f, 0.f, 0.f, 0.f};
    if (s <= s_hi) {
      for (int h = 0; h < 512; ++h) {
        float kv = kTb[(size_t)h * 512 + s];
        float vh = vL[h];
#pragma unroll
        for (int rr = 0; rr < 4; ++rr) acc[rr] = fmaf(vh, fast_tanh(qL[rr][h] + kv), acc[rr]);
      }
    }
#pragma unroll
    for (int rr = 0; rr < 4; ++rr) {
      int t = t0 + rr;
      bool valid = (s <= t) && (s < len);
      pbuf[((size_t)b * 512 + t) * 512 + s] = valid ? __expf(acc[rr] + vb - 20.f) : 0.f;
    }
  }
}

// ---------------------------------------------------------------- K5: invl[row] = 1 / sum_s p[row][s]
__global__ __launch_bounds__(256) void k_rowinv(const float* __restrict__ pbuf, float* __restrict__ invl) {
  int row = blockIdx.x * 4 + (threadIdx.x >> 6);
  int lane = threadIdx.x & 63;
  const float* pr = pbuf + (size_t)row * 512;
  float s = 0.f;
#pragma unroll
  for (int i = 0; i < 8; ++i) s += pr[lane + i * 64];
#pragma unroll
  for (int m = 1; m < 64; m <<= 1) s += __shfl_xor(s, m);
  if (lane == 0) invl[row] = 1.0f / s;
}

// ---------------------------------------------------------------- K5b: feats[:, 0:512] = bf16(out)
__global__ __launch_bounds__(256) void k_cvt_out_feats(const float* __restrict__ out,
                                                       unsigned short* __restrict__ feats) {
  int i = (blockIdx.x * 256 + threadIdx.x) * 8;
  int m = i >> 9, c = i & 511;
  float4 a = *(const float4*)(out + i);
  float4 b = *(const float4*)(out + i + 4);
  short8 v;
  v[0] = bf16r(a.x); v[1] = bf16r(a.y); v[2] = bf16r(a.z); v[3] = bf16r(a.w);
  v[4] = bf16r(b.x); v[5] = bf16r(b.y); v[6] = bf16r(b.z); v[7] = bf16r(b.w);
  *(short8*)(feats + (size_t)m * 1024 + c) = v;
}

// ---------------------------------------------------------------- K6: feats[:, 512:1024] = bf16((p @ out) * invl)
__global__ __launch_bounds__(256) void k_context(const float* __restrict__ pbuf, const float* __restrict__ out,
                                                 const float* __restrict__ invl, unsigned short* __restrict__ feats) {
  __shared__ float Pt[64][128];
  __shared__ float Ot[128][64];
  const int b = blockIdx.z, t0 = blockIdx.y * 64, h0 = blockIdx.x * 64;
  const int tid = threadIdx.x, ty = tid >> 4, tx = tid & 15;
  float acc[4][4] = {};
  for (int sc = 0; sc < 512; sc += 128) {
#pragma unroll
    for (int rr = 0; rr < 8; ++rr) {
      int row = rr * 8 + (tid >> 5);
      int col = (tid & 31) * 4;
      *(float4*)&Pt[row][col] = *(const float4*)&pbuf[((size_t)b * 512 + t0 + row) * 512 + sc + col];
    }
#pragma unroll
    for (int rr = 0; rr < 8; ++rr) {
      int srow = rr * 16 + (tid >> 4);
      int col = (tid & 15) * 4;
      *(float4*)&Ot[srow][col] = *(const float4*)&out[((size_t)b * 512 + sc + srow) * 512 + h0 + col];
    }
    __syncthreads();
    for (int kk = 0; kk < 128; ++kk) {
      float ov[4];
#pragma unroll
      for (int c = 0; c < 4; ++c) ov[c] = Ot[kk][tx * 4 + c];
#pragma unroll
      for (int a = 0; a < 4; ++a) {
        float pv = Pt[ty * 4 + a][kk];
#pragma unroll
        for (int c = 0; c < 4; ++c) acc[a][c] = fmaf(pv, ov[c], acc[a][c]);
      }
    }
    __syncthreads();
  }
#pragma unroll
  for (int a = 0; a < 4; ++a) {
    int t = t0 + ty * 4 + a;
    float il = invl[b * 512 + t];
#pragma unroll
    for (int c = 0; c < 4; ++c) {
      int h = h0 + tx * 4 + c;
      feats[((size_t)b * 512 + t) * 1024 + 512 + h] = (unsigned short)bf16r(acc[a][c] * il);
    }
  }
}

// ---------------------------------------------------------------- K7: logits = feats @ fc_W^T + fc_b (bf16 MFMA)
__global__ __launch_bounds__(256) void k_logits(const unsigned short* __restrict__ A,
                                                const unsigned short* __restrict__ Bw,
                                                const float* __restrict__ bias, float* __restrict__ C) {
  __shared__ unsigned short As[128 * 64];
  __shared__ unsigned short Bs[128 * 64];
  const int tid = threadIdx.x;
  const int wave = tid >> 6, lane = tid & 63;
  const int m0 = blockIdx.x * 128, n0 = blockIdx.y * 128;
  const int wm = (wave >> 1) * 64, wn = (wave & 1) * 64;
  const int lo16 = lane & 15, oct = lane >> 4;
  f32x4 acc[4][4] = {};
  for (int kt = 0; kt < 1024; kt += 64) {
#pragma unroll
    for (int i = 0; i < 4; ++i) {
      int ci = wave * 4 + i;
      int mrow = ci * 8 + (lane >> 3);
      int k8 = (lane & 7) * 8;
      glds16(&A[(size_t)(m0 + mrow) * 1024 + kt + k8], &As[ci * 512]);
      glds16(&Bw[(size_t)(n0 + mrow) * 1024 + kt + k8], &Bs[ci * 512]);
    }
    __syncthreads();
#pragma unroll
    for (int kk = 0; kk < 2; ++kk) {
      short8 af[4], bf[4];
#pragma unroll
      for (int i = 0; i < 4; ++i)
        af[i] = *(const short8*)&As[(wm + i * 16 + lo16) * 64 + kk * 32 + oct * 8];
#pragma unroll
      for (int jn = 0; jn < 4; ++jn)
        bf[jn] = *(const short8*)&Bs[(wn + jn * 16 + lo16) * 64 + kk * 32 + oct * 8];
#pragma unroll
      for (int i = 0; i < 4; ++i)
#pragma unroll
        for (int jn = 0; jn < 4; ++jn)
          acc[i][jn] = __builtin_amdgcn_mfma_f32_16x16x32_bf16(af[i], bf[jn], acc[i][jn], 0, 0, 0);
    }
    __syncthreads();
  }
#pragma unroll
  for (int jn = 0; jn < 4; ++jn) {
    int nn = n0 + wn + jn * 16 + lo16;
    float bv = bias[nn];
#pragma unroll
    for (int i = 0; i < 4; ++i) {
      int mbase = m0 + wm + i * 16 + oct * 4;
#pragma unroll
      for (int rr = 0; rr < 4; ++rr)
        C[(size_t)(mbase + rr) * 32000 + nn] = acc[i][jn][rr] + bv;
    }
  }
}

// ---------------------------------------------------------------- launch
extern "C" void kernel_launch(void* const* d_in, const int* in_sizes, int n_in,
                              void* d_out, int out_size, void* d_ws, size_t ws_size,
                              hipStream_t stream) {
  const int* x = (const int*)d_in[0];
  const int* lengths = (const int*)d_in[1];
  const float* embed = (const float*)d_in[2];
  const float* W_ih = (const float*)d_in[3];
  const float* W_hh = (const float*)d_in[4];
  const float* b_ih = (const float*)d_in[5];
  const float* b_hh = (const float*)d_in[6];
  const float* attn_W = (const float*)d_in[7];
  const float* attn_b = (const float*)d_in[8];
  const float* attn_v = (const float*)d_in[9];
  const float* attn_v_b = (const float*)d_in[10];
  const float* fc_W = (const float*)d_in[11];
  const float* fc_b = (const float*)d_in[12];
  float* logits = (float*)d_out;

  char* ws = (char*)d_ws;
  const size_t MB8 = 8388608;
  float* xin  = (float*)(ws);
  float* outp = (float*)(ws + 1 * MB8);
  float* q    = (float*)(ws + 2 * MB8);
  float* kT   = (float*)(ws + 3 * MB8);
  float* pbuf = (float*)(ws + 4 * MB8);
  float* invl = (float*)(ws + 5 * MB8);
  unsigned short* feats = (unsigned short*)(ws + 5 * MB8 + 16384);
  unsigned short* fcWb  = (unsigned short*)(ws + 6 * MB8 + 16384);
  char* hstate = ws + 6 * MB8 + 16384 + 65536000;
  unsigned int* hhi32 = (unsigned int*)(hstate);             // [2][8][256] u32 (bf16 hi pairs), 16 KB
  unsigned int* hlo32 = (unsigned int*)(hstate + 16384);     // [2][8][256] u32 (bf16 lo pairs), 16 KB
  int* flags = (int*)(hstate + 32768);                       // 8 ints

  hipMemsetAsync(hstate, 0, 33024, stream);
  k_cvt_bf16<<<16000, 256, 0, stream>>>(fc_W, fcWb, 32768000);
  k_xin<<<dim3(64, 8), 256, 0, stream>>>(x, embed, W_ih, b_ih, xin);
  k_rnn<<<8, 512, 0, stream>>>(xin, W_hh, b_hh, lengths, hhi32, hlo32, flags, outp);
  k_qk<0><<<dim3(64, 8), 256, 0, stream>>>(outp, attn_W, attn_b, q);
  k_qk<1><<<dim3(64, 8), 256, 0, stream>>>(outp, attn_W, attn_b, kT);
  k_scores<<<dim3(8, 128), 256, 0, stream>>>(q, kT, attn_v, attn_v_b, lengths, pbuf);
  k_rowinv<<<1024, 256, 0, stream>>>(pbuf, invl);
  k_cvt_out_feats<<<1024, 256, 0, stream>>>(outp, feats);
  k_context<<<dim3(8, 8, 8), 256, 0, stream>>>(pbuf, outp, invl, feats);
  k_logits<<<dim3(32, 250), 256, 0, stream>>>(feats, fcWb, fc_b, logits);
}

// Round 3
// 4941.996 us; speedup vs baseline: 1.3715x; 1.0607x over previous
//
#include <hip/hip_runtime.h>
#include <hip/hip_bf16.h>

// Problem constants: B=8, T=512, V=32000, E=256, H=512
typedef __attribute__((ext_vector_type(8))) short short8;
typedef __attribute__((ext_vector_type(4))) float f32x4;

#define AL64(p)    __hip_atomic_load((p), __ATOMIC_RELAXED, __HIP_MEMORY_SCOPE_AGENT)
#define AS64(p, v) __hip_atomic_store((p), (v), __ATOMIC_RELAXED, __HIP_MEMORY_SCOPE_AGENT)

__device__ __forceinline__ void glds16(const void* g, void* l) {
  __builtin_amdgcn_global_load_lds(
      (const __attribute__((address_space(1))) unsigned int*)g,
      (__attribute__((address_space(3))) unsigned int*)l, 16, 0, 0);
}

__device__ __forceinline__ float fast_tanh(float x) {
  float e = __expf(2.0f * x);
  return (e - 1.0f) * __builtin_amdgcn_rcpf(e + 1.0f);
}

__device__ __forceinline__ unsigned short bfh(float f) {
  __hip_bfloat16 h = __float2bfloat16(f);
  return *reinterpret_cast<unsigned short*>(&h);
}
__device__ __forceinline__ float bf2f(unsigned short u) {
  unsigned v = ((unsigned)u) << 16;
  float f;
  __builtin_memcpy(&f, &v, 4);
  return f;
}
__device__ __forceinline__ short bf16r(float f) { return (short)bfh(f); }

union FragU {
  unsigned int u[4];
  short8 s;
};

// ---------------------------------------------------------------- K0: fp32 -> bf16 bulk convert
__global__ __launch_bounds__(256) void k_cvt_bf16(const float* __restrict__ src,
                                                  unsigned short* __restrict__ dst, int n) {
  int i = (blockIdx.x * 256 + threadIdx.x) * 8;
  if (i >= n) return;
  float4 a = *(const float4*)(src + i);
  float4 b = *(const float4*)(src + i + 4);
  short8 v;
  v[0] = bf16r(a.x); v[1] = bf16r(a.y); v[2] = bf16r(a.z); v[3] = bf16r(a.w);
  v[4] = bf16r(b.x); v[5] = bf16r(b.y); v[6] = bf16r(b.z); v[7] = bf16r(b.w);
  *(short8*)(dst + i) = v;
}

// ---------------------------------------------------------------- K1: xin = emb(x) @ W_ih^T + b_ih
__global__ __launch_bounds__(256) void k_xin(const int* __restrict__ x, const float* __restrict__ embed,
                                             const float* __restrict__ W_ih, const float* __restrict__ b_ih,
                                             float* __restrict__ xin) {
  __shared__ float At[64][128];
  __shared__ float Bt[128][64];
  const int tid = threadIdx.x;
  const int bt0 = blockIdx.x * 64, j0 = blockIdx.y * 64;
  const int ty = tid >> 4, tx = tid & 15;
  const int lane = tid & 63, cgrp = tid >> 6;
  float acc[4][4] = {};
  for (int kc = 0; kc < 256; kc += 128) {
#pragma unroll
    for (int rr = 0; rr < 8; ++rr) {
      int row = rr * 8 + (tid >> 5);
      int col = (tid & 31) * 4;
      int tok = x[bt0 + row];
      float4 v = make_float4(0.f, 0.f, 0.f, 0.f);
      if (tok != 0) v = *(const float4*)&embed[(size_t)tok * 256 + kc + col];
      *(float4*)&At[row][col] = v;
    }
#pragma unroll
    for (int cc = 0; cc < 8; ++cc) {
      int col = cgrp * 32 + cc * 4;
      float4 v = *(const float4*)&W_ih[(size_t)(j0 + lane) * 256 + kc + col];
      Bt[col + 0][lane] = v.x; Bt[col + 1][lane] = v.y;
      Bt[col + 2][lane] = v.z; Bt[col + 3][lane] = v.w;
    }
    __syncthreads();
    for (int kk = 0; kk < 128; ++kk) {
      float bv[4];
#pragma unroll
      for (int c = 0; c < 4; ++c) bv[c] = Bt[kk][tx * 4 + c];
#pragma unroll
      for (int a = 0; a < 4; ++a) {
        float av = At[ty * 4 + a][kk];
#pragma unroll
        for (int c = 0; c < 4; ++c) acc[a][c] = fmaf(av, bv[c], acc[a][c]);
      }
    }
    __syncthreads();
  }
#pragma unroll
  for (int a = 0; a < 4; ++a) {
    int m = bt0 + ty * 4 + a;
#pragma unroll
    for (int c = 0; c < 4; ++c) {
      int j = j0 + tx * 4 + c;
      xin[(size_t)m * 512 + j] = acc[a][c] + b_ih[j];
    }
  }
}

// ---------------------------------------------------------------- K2: persistent RNN scan, data-as-flag LLC exchange
// 8 blocks x 512 thr (8 waves). Block owns j-window [64*blk, 64*blk+64).
// Wave w: j-tile = w&3 (16 j), K-half = w>>2 (8 chunks of K=32).
// h exchanged via hpub[512 slots][8 b][256 pairs] u64 = {bf16-hi pair, bf16-lo pair}.
// Slots pre-filled 0xFF (bf16 NaN pattern = impossible for tanh) -> consumers
// spin on the data itself; u64 atomicity makes each word self-validating.
// No flags, no fences, no store-ack drains on the critical path.
__global__ __launch_bounds__(512) void k_rnn(const float* __restrict__ xin, const float* __restrict__ W_hh,
                                             const float* __restrict__ b_hh, const int* __restrict__ lengths,
                                             unsigned long long* hpub, float* __restrict__ out) {
  const int blk = blockIdx.x, tid = threadIdx.x;
  const int w = tid >> 6, l = tid & 63;
  const int jt = w & 3, kh = w >> 2;
  const int j16 = blk * 64 + jt * 16;
  const int r = l & 15;   // A row (= batch b), valid r<8
  const int g = l >> 4;   // k-group
  const int n = l & 15;   // B col (= j within tile)

  __shared__ f32x4 Cbuf[2][4][64];  // parity double-buffer for cross-K-half reduce

  // ---- preload W fragments (bf16 hi/lo), 8 chunks per wave
  short8 bhi[8], blo[8];
  {
    const float* wrow = &W_hh[(size_t)(j16 + n) * 512];
#pragma unroll
    for (int c8 = 0; c8 < 8; ++c8) {
      int c = kh * 8 + c8;
      const float* wp = wrow + c * 32 + g * 8;
      float4 wa = *(const float4*)wp;
      float4 wb = *(const float4*)(wp + 4);
      float wv[8] = {wa.x, wa.y, wa.z, wa.w, wb.x, wb.y, wb.z, wb.w};
#pragma unroll
      for (int e = 0; e < 8; ++e) {
        unsigned short h = bfh(wv[e]);
        bhi[c8][e] = (short)h;
        blo[c8][e] = (short)bfh(wv[e] - bf2f(h));
      }
    }
  }

  // ---- per-lane epilogue constants (waves 0..3, lanes 0..31)
  float bj = 0.f, xv[4];
  int len4[4];
  if (w < 4 && l < 32) {
    bj = b_hh[j16 + n];
#pragma unroll
    for (int i = 0; i < 4; ++i) {
      int b = g * 4 + i;
      len4[i] = lengths[b];
      xv[i] = xin[((size_t)b * 512 + 0) * 512 + j16 + n];  // t=0
    }
  }

  for (int t = 0; t < 512; ++t) {
    // ---- sentinel-poll the A fragments for step t
    unsigned long long u[8][4];
    if (r < 8) {
      const unsigned long long* base = hpub + (size_t)t * 2048 + r * 256 + kh * 128 + g * 4;
      bool ok = false;
      int guard = 0;
      while (!ok && guard++ < (1 << 18)) {
#pragma unroll
        for (int c8 = 0; c8 < 8; ++c8)
#pragma unroll
          for (int q = 0; q < 4; ++q)
            u[c8][q] = AL64(base + c8 * 16 + q);
        ok = true;
#pragma unroll
        for (int c8 = 0; c8 < 8; ++c8)
#pragma unroll
          for (int q = 0; q < 4; ++q)
            ok = ok && ((unsigned)u[c8][q] != 0xFFFFFFFFu);
      }
    } else {
#pragma unroll
      for (int c8 = 0; c8 < 8; ++c8)
#pragma unroll
        for (int q = 0; q < 4; ++q) u[c8][q] = 0ull;
    }

    // ---- split-bf16 MFMA accumulate (hi*hi + hi*lo + lo*hi)
    f32x4 acc0 = {}, acc1 = {};
#pragma unroll
    for (int c8 = 0; c8 < 8; ++c8) {
      FragU ah, al;
#pragma unroll
      for (int q = 0; q < 4; ++q) {
        ah.u[q] = (unsigned)u[c8][q];
        al.u[q] = (unsigned)(u[c8][q] >> 32);
      }
      if (c8 & 1) {
        acc1 = __builtin_amdgcn_mfma_f32_16x16x32_bf16(ah.s, bhi[c8], acc1, 0, 0, 0);
        acc1 = __builtin_amdgcn_mfma_f32_16x16x32_bf16(ah.s, blo[c8], acc1, 0, 0, 0);
        acc1 = __builtin_amdgcn_mfma_f32_16x16x32_bf16(al.s, bhi[c8], acc1, 0, 0, 0);
      } else {
        acc0 = __builtin_amdgcn_mfma_f32_16x16x32_bf16(ah.s, bhi[c8], acc0, 0, 0, 0);
        acc0 = __builtin_amdgcn_mfma_f32_16x16x32_bf16(ah.s, blo[c8], acc0, 0, 0, 0);
        acc0 = __builtin_amdgcn_mfma_f32_16x16x32_bf16(al.s, bhi[c8], acc0, 0, 0, 0);
      }
    }
    f32x4 tot = acc0 + acc1;

    // ---- cross-K-half reduce via LDS (parity-buffered; single barrier per step)
    if (w >= 4) Cbuf[t & 1][w - 4][l] = tot;
    __syncthreads();
    if (w < 4) {
      tot += Cbuf[t & 1][w][l];
      if (l < 32) {
        unsigned pk[4];
#pragma unroll
        for (int i = 0; i < 4; ++i) {
          int b = g * 4 + i;
          float hn = fast_tanh(xv[i] + tot[i] + bj);
          out[((size_t)b * 512 + t) * 512 + j16 + n] = (t < len4[i]) ? hn : 0.f;
          unsigned hi = bfh(hn);
          unsigned lo = bfh(hn - bf2f((unsigned short)hi));
          pk[i] = hi | (lo << 16);
        }
        int tt = (t < 511) ? t + 1 : 511;
#pragma unroll
        for (int i = 0; i < 4; ++i)
          xv[i] = xin[((size_t)(g * 4 + i) * 512 + tt) * 512 + j16 + n];
        if (t < 511) {
          unsigned long long* hw = hpub + (size_t)(t + 1) * 2048;
#pragma unroll
          for (int i = 0; i < 4; ++i) {
            unsigned other = __shfl_xor(pk[i], 1);
            if ((n & 1) == 0) {
              unsigned hipr = (pk[i] & 0xFFFFu) | ((other & 0xFFFFu) << 16);
              unsigned lopr = (pk[i] >> 16) | (other & 0xFFFF0000u);
              unsigned long long val = (unsigned long long)hipr | ((unsigned long long)lopr << 32);
              AS64(hw + (g * 4 + i) * 256 + ((j16 + n) >> 1), val);  // fire-and-forget
            }
          }
        }
      }
    }
  }
}

// ---------------------------------------------------------------- K3: q = out@W1^T ; kT = out@W2^T + b
template <int MODE>
__global__ __launch_bounds__(256) void k_qk(const float* __restrict__ out, const float* __restrict__ attn_W,
                                            const float* __restrict__ attn_b, float* __restrict__ dst) {
  __shared__ float At[64][128];
  __shared__ float Bt[128][64];
  const int tid = threadIdx.x;
  const int bt0 = blockIdx.x * 64, j0 = blockIdx.y * 64;
  const int ty = tid >> 4, tx = tid & 15;
  const int lane = tid & 63, cgrp = tid >> 6;
  float acc[4][4] = {};
  for (int kc = 0; kc < 512; kc += 128) {
#pragma unroll
    for (int rr = 0; rr < 8; ++rr) {
      int row = rr * 8 + (tid >> 5);
      int col = (tid & 31) * 4;
      *(float4*)&At[row][col] = *(const float4*)&out[((size_t)bt0 + row) * 512 + kc + col];
    }
#pragma unroll
    for (int cc = 0; cc < 8; ++cc) {
      int col = cgrp * 32 + cc * 4;
      float4 v = *(const float4*)&attn_W[(size_t)(j0 + lane) * 1024 + (MODE ? 512 : 0) + kc + col];
      Bt[col + 0][lane] = v.x; Bt[col + 1][lane] = v.y;
      Bt[col + 2][lane] = v.z; Bt[col + 3][lane] = v.w;
    }
    __syncthreads();
    for (int kk = 0; kk < 128; ++kk) {
      float bv[4];
#pragma unroll
      for (int c = 0; c < 4; ++c) bv[c] = Bt[kk][tx * 4 + c];
#pragma unroll
      for (int a = 0; a < 4; ++a) {
        float av = At[ty * 4 + a][kk];
#pragma unroll
        for (int c = 0; c < 4; ++c) acc[a][c] = fmaf(av, bv[c], acc[a][c]);
      }
    }
    __syncthreads();
  }
#pragma unroll
  for (int a = 0; a < 4; ++a) {
    int bt = bt0 + ty * 4 + a;
#pragma unroll
    for (int c = 0; c < 4; ++c) {
      int j = j0 + tx * 4 + c;
      if (MODE == 0) {
        dst[(size_t)bt * 512 + j] = acc[a][c];
      } else {
        int bb = bt >> 9, tt = bt & 511;
        dst[((size_t)bb * 512 + j) * 512 + tt] = acc[a][c] + attn_b[j];
      }
    }
  }
}

// ---------------------------------------------------------------- K4: p[b][t][s] = exp(score-20) masked
__global__ __launch_bounds__(256) void k_scores(const float* __restrict__ q, const float* __restrict__ kT,
                                                const float* __restrict__ attn_v, const float* __restrict__ attn_v_b,
                                                const int* __restrict__ lengths, float* __restrict__ pbuf) {
  const int b = blockIdx.x, t0 = blockIdx.y * 4;
  const int tid = threadIdx.x;
  __shared__ float qL[4][512];
  __shared__ float vL[512];
  for (int i = tid; i < 4 * 512; i += 256) {
    int rr = i >> 9, h = i & 511;
    qL[rr][h] = q[((size_t)b * 512 + t0 + rr) * 512 + h];
  }
  for (int i = tid; i < 512; i += 256) vL[i] = attn_v[i];
  const float vb = attn_v_b[0];
  const int len = lengths[b];
  __syncthreads();
  const int s_hi = min(t0 + 3, len - 1);
  const float* kTb = kT + (size_t)b * 512 * 512;
#pragma unroll
  for (int si = 0; si < 2; ++si) {
    int s = tid + si * 256;
    float acc[4] = {0.f, 0.f, 0.f, 0.f};
    if (s <= s_hi) {
      for (int h = 0; h < 512; ++h) {
        float kv = kTb[(size_t)h * 512 + s];
        float vh = vL[h];
#pragma unroll
        for (int rr = 0; rr < 4; ++rr) acc[rr] = fmaf(vh, fast_tanh(qL[rr][h] + kv), acc[rr]);
      }
    }
#pragma unroll
    for (int rr = 0; rr < 4; ++rr) {
      int t = t0 + rr;
      bool valid = (s <= t) && (s < len);
      pbuf[((size_t)b * 512 + t) * 512 + s] = valid ? __expf(acc[rr] + vb - 20.f) : 0.f;
    }
  }
}

// ---------------------------------------------------------------- K5: invl[row] = 1 / sum_s p[row][s]
__global__ __launch_bounds__(256) void k_rowinv(const float* __restrict__ pbuf, float* __restrict__ invl) {
  int row = blockIdx.x * 4 + (threadIdx.x >> 6);
  int lane = threadIdx.x & 63;
  const float* pr = pbuf + (size_t)row * 512;
  float s = 0.f;
#pragma unroll
  for (int i = 0; i < 8; ++i) s += pr[lane + i * 64];
#pragma unroll
  for (int m = 1; m < 64; m <<= 1) s += __shfl_xor(s, m);
  if (lane == 0) invl[row] = 1.0f / s;
}

// ---------------------------------------------------------------- K5b: feats[:, 0:512] = bf16(out)
__global__ __launch_bounds__(256) void k_cvt_out_feats(const float* __restrict__ out,
                                                       unsigned short* __restrict__ feats) {
  int i = (blockIdx.x * 256 + threadIdx.x) * 8;
  int m = i >> 9, c = i & 511;
  float4 a = *(const float4*)(out + i);
  float4 b = *(const float4*)(out + i + 4);
  short8 v;
  v[0] = bf16r(a.x); v[1] = bf16r(a.y); v[2] = bf16r(a.z); v[3] = bf16r(a.w);
  v[4] = bf16r(b.x); v[5] = bf16r(b.y); v[6] = bf16r(b.z); v[7] = bf16r(b.w);
  *(short8*)(feats + (size_t)m * 1024 + c) = v;
}

// ---------------------------------------------------------------- K6: feats[:, 512:1024] = bf16((p @ out) * invl)
__global__ __launch_bounds__(256) void k_context(const float* __restrict__ pbuf, const float* __restrict__ out,
                                                 const float* __restrict__ invl, unsigned short* __restrict__ feats) {
  __shared__ float Pt[64][128];
  __shared__ float Ot[128][64];
  const int b = blockIdx.z, t0 = blockIdx.y * 64, h0 = blockIdx.x * 64;
  const int tid = threadIdx.x, ty = tid >> 4, tx = tid & 15;
  float acc[4][4] = {};
  for (int sc = 0; sc < 512; sc += 128) {
#pragma unroll
    for (int rr = 0; rr < 8; ++rr) {
      int row = rr * 8 + (tid >> 5);
      int col = (tid & 31) * 4;
      *(float4*)&Pt[row][col] = *(const float4*)&pbuf[((size_t)b * 512 + t0 + row) * 512 + sc + col];
    }
#pragma unroll
    for (int rr = 0; rr < 8; ++rr) {
      int srow = rr * 16 + (tid >> 4);
      int col = (tid & 15) * 4;
      *(float4*)&Ot[srow][col] = *(const float4*)&out[((size_t)b * 512 + sc + srow) * 512 + h0 + col];
    }
    __syncthreads();
    for (int kk = 0; kk < 128; ++kk) {
      float ov[4];
#pragma unroll
      for (int c = 0; c < 4; ++c) ov[c] = Ot[kk][tx * 4 + c];
#pragma unroll
      for (int a = 0; a < 4; ++a) {
        float pv = Pt[ty * 4 + a][kk];
#pragma unroll
        for (int c = 0; c < 4; ++c) acc[a][c] = fmaf(pv, ov[c], acc[a][c]);
      }
    }
    __syncthreads();
  }
#pragma unroll
  for (int a = 0; a < 4; ++a) {
    int t = t0 + ty * 4 + a;
    float il = invl[b * 512 + t];
#pragma unroll
    for (int c = 0; c < 4; ++c) {
      int h = h0 + tx * 4 + c;
      feats[((size_t)b * 512 + t) * 1024 + 512 + h] = (unsigned short)bf16r(acc[a][c] * il);
    }
  }
}

// ---------------------------------------------------------------- K7: logits = feats @ fc_W^T + fc_b (bf16 MFMA)
__global__ __launch_bounds__(256) void k_logits(const unsigned short* __restrict__ A,
                                                const unsigned short* __restrict__ Bw,
                                                const float* __restrict__ bias, float* __restrict__ C) {
  __shared__ unsigned short As[128 * 64];
  __shared__ unsigned short Bs[128 * 64];
  const int tid = threadIdx.x;
  const int wave = tid >> 6, lane = tid & 63;
  const int m0 = blockIdx.x * 128, n0 = blockIdx.y * 128;
  const int wm = (wave >> 1) * 64, wn = (wave & 1) * 64;
  const int lo16 = lane & 15, oct = lane >> 4;
  f32x4 acc[4][4] = {};
  for (int kt = 0; kt < 1024; kt += 64) {
#pragma unroll
    for (int i = 0; i < 4; ++i) {
      int ci = wave * 4 + i;
      int mrow = ci * 8 + (lane >> 3);
      int k8 = (lane & 7) * 8;
      glds16(&A[(size_t)(m0 + mrow) * 1024 + kt + k8], &As[ci * 512]);
      glds16(&Bw[(size_t)(n0 + mrow) * 1024 + kt + k8], &Bs[ci * 512]);
    }
    __syncthreads();
#pragma unroll
    for (int kk = 0; kk < 2; ++kk) {
      short8 af[4], bf[4];
#pragma unroll
      for (int i = 0; i < 4; ++i)
        af[i] = *(const short8*)&As[(wm + i * 16 + lo16) * 64 + kk * 32 + oct * 8];
#pragma unroll
      for (int jn = 0; jn < 4; ++jn)
        bf[jn] = *(const short8*)&Bs[(wn + jn * 16 + lo16) * 64 + kk * 32 + oct * 8];
#pragma unroll
      for (int i = 0; i < 4; ++i)
#pragma unroll
        for (int jn = 0; jn < 4; ++jn)
          acc[i][jn] = __builtin_amdgcn_mfma_f32_16x16x32_bf16(af[i], bf[jn], acc[i][jn], 0, 0, 0);
    }
    __syncthreads();
  }
#pragma unroll
  for (int jn = 0; jn < 4; ++jn) {
    int nn = n0 + wn + jn * 16 + lo16;
    float bv = bias[nn];
#pragma unroll
    for (int i = 0; i < 4; ++i) {
      int mbase = m0 + wm + i * 16 + oct * 4;
#pragma unroll
      for (int rr = 0; rr < 4; ++rr)
        C[(size_t)(mbase + rr) * 32000 + nn] = acc[i][jn][rr] + bv;
    }
  }
}

// ---------------------------------------------------------------- launch
extern "C" void kernel_launch(void* const* d_in, const int* in_sizes, int n_in,
                              void* d_out, int out_size, void* d_ws, size_t ws_size,
                              hipStream_t stream) {
  const int* x = (const int*)d_in[0];
  const int* lengths = (const int*)d_in[1];
  const float* embed = (const float*)d_in[2];
  const float* W_ih = (const float*)d_in[3];
  const float* W_hh = (const float*)d_in[4];
  const float* b_ih = (const float*)d_in[5];
  const float* b_hh = (const float*)d_in[6];
  const float* attn_W = (const float*)d_in[7];
  const float* attn_b = (const float*)d_in[8];
  const float* attn_v = (const float*)d_in[9];
  const float* attn_v_b = (const float*)d_in[10];
  const float* fc_W = (const float*)d_in[11];
  const float* fc_b = (const float*)d_in[12];
  float* logits = (float*)d_out;

  char* ws = (char*)d_ws;
  const size_t MB8 = 8388608;
  float* xin  = (float*)(ws);
  float* outp = (float*)(ws + 1 * MB8);
  float* q    = (float*)(ws + 2 * MB8);
  float* kT   = (float*)(ws + 3 * MB8);
  float* pbuf = (float*)(ws + 4 * MB8);
  float* invl = (float*)(ws + 5 * MB8);
  unsigned short* feats = (unsigned short*)(ws + 5 * MB8 + 16384);
  unsigned short* fcWb  = (unsigned short*)(ws + 6 * MB8 + 16384);
  // hpub aliases pbuf: [512 slots][8][256] u64 = 8 MB. Dead once k_rnn completes;
  // k_scores then fully overwrites pbuf.
  unsigned long long* hpub = (unsigned long long*)pbuf;

  hipMemsetAsync(pbuf, 0xFF, MB8, stream);      // sentinel all slots
  hipMemsetAsync(pbuf, 0x00, 16384, stream);    // slot 0 = h_0 = 0
  k_cvt_bf16<<<16000, 256, 0, stream>>>(fc_W, fcWb, 32768000);
  k_xin<<<dim3(64, 8), 256, 0, stream>>>(x, embed, W_ih, b_ih, xin);
  k_rnn<<<8, 512, 0, stream>>>(xin, W_hh, b_hh, lengths, hpub, outp);
  k_qk<0><<<dim3(64, 8), 256, 0, stream>>>(outp, attn_W, attn_b, q);
  k_qk<1><<<dim3(64, 8), 256, 0, stream>>>(outp, attn_W, attn_b, kT);
  k_scores<<<dim3(8, 128), 256, 0, stream>>>(q, kT, attn_v, attn_v_b, lengths, pbuf);
  k_rowinv<<<1024, 256, 0, stream>>>(pbuf, invl);
  k_cvt_out_feats<<<1024, 256, 0, stream>>>(outp, feats);
  k_context<<<dim3(8, 8, 8), 256, 0, stream>>>(pbuf, outp, invl, feats);
  k_logits<<<dim3(32, 250), 256, 0, stream>>>(feats, fcWb, fc_b, logits);
}

// Round 4
// 2759.320 us; speedup vs baseline: 2.4563x; 1.7910x over previous
//
#include <hip/hip_runtime.h>
#include <hip/hip_bf16.h>

// Problem constants: B=8, T=512, V=32000, E=256, H=512
typedef __attribute__((ext_vector_type(8))) short short8;
typedef __attribute__((ext_vector_type(4))) float f32x4;

#define AL64(p)    __hip_atomic_load((p), __ATOMIC_RELAXED, __HIP_MEMORY_SCOPE_AGENT)
#define AS64(p, v) __hip_atomic_store((p), (v), __ATOMIC_RELAXED, __HIP_MEMORY_SCOPE_AGENT)

__device__ __forceinline__ void glds16(const void* g, void* l) {
  __builtin_amdgcn_global_load_lds(
      (const __attribute__((address_space(1))) unsigned int*)g,
      (__attribute__((address_space(3))) unsigned int*)l, 16, 0, 0);
}

// Workgroup barrier that drains ONLY LDS ops (lgkmcnt) — does NOT wait for
// outstanding global stores/loads (vmcnt), unlike __syncthreads which the
// compiler precedes with a full vmcnt(0) drain. All in-loop barriers in k_rnn
// protect LDS-only data, so this keeps publish stores fully asynchronous.
__device__ __forceinline__ void bar_lds() {
  asm volatile("s_waitcnt lgkmcnt(0)\n\ts_barrier" ::: "memory");
}

__device__ __forceinline__ float fast_tanh(float x) {
  float e = __expf(2.0f * x);
  return (e - 1.0f) * __builtin_amdgcn_rcpf(e + 1.0f);
}

__device__ __forceinline__ unsigned short bfh(float f) {
  __hip_bfloat16 h = __float2bfloat16(f);
  return *reinterpret_cast<unsigned short*>(&h);
}
__device__ __forceinline__ float bf2f(unsigned short u) {
  unsigned v = ((unsigned)u) << 16;
  float f;
  __builtin_memcpy(&f, &v, 4);
  return f;
}
__device__ __forceinline__ short bf16r(float f) { return (short)bfh(f); }

union FragU {
  unsigned int u[4];
  short8 s;
};

// ---------------------------------------------------------------- K0: fp32 -> bf16 bulk convert
__global__ __launch_bounds__(256) void k_cvt_bf16(const float* __restrict__ src,
                                                  unsigned short* __restrict__ dst, int n) {
  int i = (blockIdx.x * 256 + threadIdx.x) * 8;
  if (i >= n) return;
  float4 a = *(const float4*)(src + i);
  float4 b = *(const float4*)(src + i + 4);
  short8 v;
  v[0] = bf16r(a.x); v[1] = bf16r(a.y); v[2] = bf16r(a.z); v[3] = bf16r(a.w);
  v[4] = bf16r(b.x); v[5] = bf16r(b.y); v[6] = bf16r(b.z); v[7] = bf16r(b.w);
  *(short8*)(dst + i) = v;
}

// ---------------------------------------------------------------- K1: xin = emb(x) @ W_ih^T + b_ih
__global__ __launch_bounds__(256) void k_xin(const int* __restrict__ x, const float* __restrict__ embed,
                                             const float* __restrict__ W_ih, const float* __restrict__ b_ih,
                                             float* __restrict__ xin) {
  __shared__ float At[64][128];
  __shared__ float Bt[128][64];
  const int tid = threadIdx.x;
  const int bt0 = blockIdx.x * 64, j0 = blockIdx.y * 64;
  const int ty = tid >> 4, tx = tid & 15;
  const int lane = tid & 63, cgrp = tid >> 6;
  float acc[4][4] = {};
  for (int kc = 0; kc < 256; kc += 128) {
#pragma unroll
    for (int rr = 0; rr < 8; ++rr) {
      int row = rr * 8 + (tid >> 5);
      int col = (tid & 31) * 4;
      int tok = x[bt0 + row];
      float4 v = make_float4(0.f, 0.f, 0.f, 0.f);
      if (tok != 0) v = *(const float4*)&embed[(size_t)tok * 256 + kc + col];
      *(float4*)&At[row][col] = v;
    }
#pragma unroll
    for (int cc = 0; cc < 8; ++cc) {
      int col = cgrp * 32 + cc * 4;
      float4 v = *(const float4*)&W_ih[(size_t)(j0 + lane) * 256 + kc + col];
      Bt[col + 0][lane] = v.x; Bt[col + 1][lane] = v.y;
      Bt[col + 2][lane] = v.z; Bt[col + 3][lane] = v.w;
    }
    __syncthreads();
    for (int kk = 0; kk < 128; ++kk) {
      float bv[4];
#pragma unroll
      for (int c = 0; c < 4; ++c) bv[c] = Bt[kk][tx * 4 + c];
#pragma unroll
      for (int a = 0; a < 4; ++a) {
        float av = At[ty * 4 + a][kk];
#pragma unroll
        for (int c = 0; c < 4; ++c) acc[a][c] = fmaf(av, bv[c], acc[a][c]);
      }
    }
    __syncthreads();
  }
#pragma unroll
  for (int a = 0; a < 4; ++a) {
    int m = bt0 + ty * 4 + a;
#pragma unroll
    for (int c = 0; c < 4; ++c) {
      int j = j0 + tx * 4 + c;
      xin[(size_t)m * 512 + j] = acc[a][c] + b_ih[j];
    }
  }
}

// ---------------------------------------------------------------- K2: persistent RNN scan — private mailboxes + LDS dedup
// 8 blocks x 512 thr. Block owns j-window [64*blk, 64*blk+64).
// mbox[dst 0..7][slot 0..15][2048 u64]: slot holds full h_t (u64 = hi-pair | lo-pair<<32,
// word index = b*256 + jpair). Producer block writes its 256-word slice to ALL 8
// mailboxes (1 reader per word -> no LLC hot lines). Consumer stages its own
// mailbox slot into LDS once (sentinel-polled, 2-barrier LDS flag protocol),
// re-sentinels, then all waves read MFMA fragments from LDS.
// All in-loop barriers are lgkm-only: global stores never block the pipeline.
__global__ __launch_bounds__(512) void k_rnn(const float* __restrict__ xin, const float* __restrict__ W_hh,
                                             const float* __restrict__ b_hh, const int* __restrict__ lengths,
                                             unsigned long long* mbox, float* __restrict__ out) {
  const int blk = blockIdx.x, tid = threadIdx.x;
  const int w = tid >> 6, l = tid & 63;
  const int jt = w & 3, kh = w >> 2;
  const int j16 = blk * 64 + jt * 16;
  const int r = l & 15;   // A row (= batch b), valid r<8
  const int g = l >> 4;   // k-group
  const int n = l & 15;   // B col (= j within tile)

  __shared__ unsigned long long stg[2048];  // 16 KB staged h (XOR-swizzled)
  __shared__ f32x4 Cbuf[4][64];             // cross-K-half partial sums
  __shared__ float hLf[8][64];              // exact fp32 h slice (for out)
  __shared__ unsigned int hL32[8][64];      // packed {hi,lo} bf16 (for publish)
  __shared__ int nflag[2];

  // ---- preload W fragments (bf16 hi/lo), 8 chunks per wave (verbatim R3)
  short8 bhi[8], blo[8];
  {
    const float* wrow = &W_hh[(size_t)(j16 + n) * 512];
#pragma unroll
    for (int c8 = 0; c8 < 8; ++c8) {
      int c = kh * 8 + c8;
      const float* wp = wrow + c * 32 + g * 8;
      float4 wa = *(const float4*)wp;
      float4 wb = *(const float4*)(wp + 4);
      float wv[8] = {wa.x, wa.y, wa.z, wa.w, wb.x, wb.y, wb.z, wb.w};
#pragma unroll
      for (int e = 0; e < 8; ++e) {
        unsigned short h = bfh(wv[e]);
        bhi[c8][e] = (short)h;
        blo[c8][e] = (short)bfh(wv[e] - bf2f(h));
      }
    }
  }

  // ---- per-lane epilogue constants (producer lanes: waves 0..3, lanes 0..31)
  float bj = 0.f, xv[4];
  if (w < 4 && l < 32) {
    bj = b_hh[j16 + n];
#pragma unroll
    for (int i = 0; i < 4; ++i)
      xv[i] = xin[((size_t)(g * 4 + i) * 512 + 0) * 512 + j16 + n];  // t=0
  }
  const int mylen = lengths[tid >> 6 & 7];  // b = tid>>6 for the out-store phase

  if (tid < 2) nflag[tid] = 0;
  __syncthreads();

  const unsigned long long SENT = ~0ull;

  for (int t = 0; t < 512; ++t) {
    // ================ poll own mailbox slot (t&15), stage into LDS ================
    {
      unsigned long long* src = mbox + ((size_t)blk * 16 + (t & 15)) * 2048 + tid * 4;
      const int idx0 = tid * 4;
      const unsigned swz = ((idx0 >> 8) & 7) << 1;  // u64-index XOR (= byte ^ (b&7)<<4)
      bool mine = false;
      int round = 0;
      while (true) {
        if (!mine) {
          unsigned long long v0 = AL64(src + 0), v1 = AL64(src + 1);
          unsigned long long v2 = AL64(src + 2), v3 = AL64(src + 3);
          if ((unsigned)v0 != 0xFFFFFFFFu && (unsigned)v1 != 0xFFFFFFFFu &&
              (unsigned)v2 != 0xFFFFFFFFu && (unsigned)v3 != 0xFFFFFFFFu) {
            mine = true;
            stg[(idx0 + 0) ^ swz] = v0; stg[(idx0 + 1) ^ swz] = v1;
            stg[(idx0 + 2) ^ swz] = v2; stg[(idx0 + 3) ^ swz] = v3;
            AS64(src + 0, SENT); AS64(src + 1, SENT);  // re-sentinel (fire & forget)
            AS64(src + 2, SENT); AS64(src + 3, SENT);
          }
        }
        int p = round & 1;
        if (!mine) nflag[p] = 1;
        bar_lds();
        int bad = nflag[p];
        if (tid == 0) nflag[p ^ 1] = 0;
        bar_lds();
        if (!bad) break;
        if (++round == 4096) break;  // bug guard -> visible absmax failure
      }
    }

    // ================ MFMA from LDS-staged fragments ================
    f32x4 acc0 = {}, acc1 = {};
#pragma unroll
    for (int c8 = 0; c8 < 8; ++c8) {
      FragU ah, al;
      if (r < 8) {
        int i0 = r * 256 + kh * 128 + c8 * 16 + g * 4;
        unsigned sw = ((i0 >> 8) & 7) << 1;
        unsigned long long u0 = stg[(i0 + 0) ^ sw], u1 = stg[(i0 + 1) ^ sw];
        unsigned long long u2 = stg[(i0 + 2) ^ sw], u3 = stg[(i0 + 3) ^ sw];
        ah.u[0] = (unsigned)u0; al.u[0] = (unsigned)(u0 >> 32);
        ah.u[1] = (unsigned)u1; al.u[1] = (unsigned)(u1 >> 32);
        ah.u[2] = (unsigned)u2; al.u[2] = (unsigned)(u2 >> 32);
        ah.u[3] = (unsigned)u3; al.u[3] = (unsigned)(u3 >> 32);
      } else {
        ah.u[0] = ah.u[1] = ah.u[2] = ah.u[3] = 0u;
        al.u[0] = al.u[1] = al.u[2] = al.u[3] = 0u;
      }
      if (c8 & 1) {
        acc1 = __builtin_amdgcn_mfma_f32_16x16x32_bf16(ah.s, bhi[c8], acc1, 0, 0, 0);
        acc1 = __builtin_amdgcn_mfma_f32_16x16x32_bf16(ah.s, blo[c8], acc1, 0, 0, 0);
        acc1 = __builtin_amdgcn_mfma_f32_16x16x32_bf16(al.s, bhi[c8], acc1, 0, 0, 0);
      } else {
        acc0 = __builtin_amdgcn_mfma_f32_16x16x32_bf16(ah.s, bhi[c8], acc0, 0, 0, 0);
        acc0 = __builtin_amdgcn_mfma_f32_16x16x32_bf16(ah.s, blo[c8], acc0, 0, 0, 0);
        acc0 = __builtin_amdgcn_mfma_f32_16x16x32_bf16(al.s, bhi[c8], acc0, 0, 0, 0);
      }
    }
    f32x4 tot = acc0 + acc1;

    // ================ cross-K-half reduce + tanh ================
    if (w >= 4) Cbuf[w - 4][l] = tot;
    bar_lds();  // B1
    if (w < 4) {
      tot += Cbuf[w][l];
      if (l < 32) {
#pragma unroll
        for (int i = 0; i < 4; ++i) {
          int b = g * 4 + i;
          float hn = fast_tanh(xv[i] + tot[i] + bj);
          hLf[b][jt * 16 + n] = hn;
          unsigned hi = bfh(hn);
          unsigned lo = bfh(hn - bf2f((unsigned short)hi));
          hL32[b][jt * 16 + n] = hi | (lo << 16);
        }
        int tt = (t < 511) ? t + 1 : 511;
#pragma unroll
        for (int i = 0; i < 4; ++i)
          xv[i] = xin[((size_t)(g * 4 + i) * 512 + tt) * 512 + j16 + n];
      }
    }
    bar_lds();  // B2: hLf / hL32 ready

    // ================ out store (all 512 threads, coalesced) ================
    {
      int b = tid >> 6, jl = tid & 63;
      float hv = hLf[b][jl];
      out[((size_t)b * 512 + t) * 512 + blk * 64 + jl] = (t < mylen) ? hv : 0.f;
    }

    // ================ publish h_{t+1} slice to all 8 mailboxes ================
    // wave w -> mailbox w; 4 u64 per thread; stores are never waited on.
    if (t < 511) {
      unsigned long long* dst = mbox + ((size_t)w * 16 + ((t + 1) & 15)) * 2048 + blk * 32;
#pragma unroll
      for (int k2 = 0; k2 < 4; ++k2) {
        int idx = l + k2 * 64;            // 0..255 = b*32 + jpl
        int b = idx >> 5, jpl = idx & 31;
        unsigned u0 = hL32[b][jpl * 2], u1 = hL32[b][jpl * 2 + 1];
        unsigned hipr = (u0 & 0xffffu) | (u1 << 16);
        unsigned lopr = (u0 >> 16) | (u1 & 0xffff0000u);
        AS64(dst + b * 256 + jpl, (unsigned long long)hipr | ((unsigned long long)lopr << 32));
      }
    }
    // no trailing barrier: next step's poll barriers pace LDS reuse safely.
  }
}

// ---------------------------------------------------------------- K3: q = out@W1^T ; kT = out@W2^T + b
template <int MODE>
__global__ __launch_bounds__(256) void k_qk(const float* __restrict__ out, const float* __restrict__ attn_W,
                                            const float* __restrict__ attn_b, float* __restrict__ dst) {
  __shared__ float At[64][128];
  __shared__ float Bt[128][64];
  const int tid = threadIdx.x;
  const int bt0 = blockIdx.x * 64, j0 = blockIdx.y * 64;
  const int ty = tid >> 4, tx = tid & 15;
  const int lane = tid & 63, cgrp = tid >> 6;
  float acc[4][4] = {};
  for (int kc = 0; kc < 512; kc += 128) {
#pragma unroll
    for (int rr = 0; rr < 8; ++rr) {
      int row = rr * 8 + (tid >> 5);
      int col = (tid & 31) * 4;
      *(float4*)&At[row][col] = *(const float4*)&out[((size_t)bt0 + row) * 512 + kc + col];
    }
#pragma unroll
    for (int cc = 0; cc < 8; ++cc) {
      int col = cgrp * 32 + cc * 4;
      float4 v = *(const float4*)&attn_W[(size_t)(j0 + lane) * 1024 + (MODE ? 512 : 0) + kc + col];
      Bt[col + 0][lane] = v.x; Bt[col + 1][lane] = v.y;
      Bt[col + 2][lane] = v.z; Bt[col + 3][lane] = v.w;
    }
    __syncthreads();
    for (int kk = 0; kk < 128; ++kk) {
      float bv[4];
#pragma unroll
      for (int c = 0; c < 4; ++c) bv[c] = Bt[kk][tx * 4 + c];
#pragma unroll
      for (int a = 0; a < 4; ++a) {
        float av = At[ty * 4 + a][kk];
#pragma unroll
        for (int c = 0; c < 4; ++c) acc[a][c] = fmaf(av, bv[c], acc[a][c]);
      }
    }
    __syncthreads();
  }
#pragma unroll
  for (int a = 0; a < 4; ++a) {
    int bt = bt0 + ty * 4 + a;
#pragma unroll
    for (int c = 0; c < 4; ++c) {
      int j = j0 + tx * 4 + c;
      if (MODE == 0) {
        dst[(size_t)bt * 512 + j] = acc[a][c];
      } else {
        int bb = bt >> 9, tt = bt & 511;
        dst[((size_t)bb * 512 + j) * 512 + tt] = acc[a][c] + attn_b[j];
      }
    }
  }
}

// ---------------------------------------------------------------- K4: p[b][t][s] = exp(score-20) masked
__global__ __launch_bounds__(256) void k_scores(const float* __restrict__ q, const float* __restrict__ kT,
                                                const float* __restrict__ attn_v, const float* __restrict__ attn_v_b,
                                                const int* __restrict__ lengths, float* __restrict__ pbuf) {
  const int b = blockIdx.x, t0 = blockIdx.y * 4;
  const int tid = threadIdx.x;
  __shared__ float qL[4][512];
  __shared__ float vL[512];
  for (int i = tid; i < 4 * 512; i += 256) {
    int rr = i >> 9, h = i & 511;
    qL[rr][h] = q[((size_t)b * 512 + t0 + rr) * 512 + h];
  }
  for (int i = tid; i < 512; i += 256) vL[i] = attn_v[i];
  const float vb = attn_v_b[0];
  const int len = lengths[b];
  __syncthreads();
  const int s_hi = min(t0 + 3, len - 1);
  const float* kTb = kT + (size_t)b * 512 * 512;
#pragma unroll
  for (int si = 0; si < 2; ++si) {
    int s = tid + si * 256;
    float acc[4] = {0.f, 0.f, 0.f, 0.f};
    if (s <= s_hi) {
      for (int h = 0; h < 512; ++h) {
        float kv = kTb[(size_t)h * 512 + s];
        float vh = vL[h];
#pragma unroll
        for (int rr = 0; rr < 4; ++rr) acc[rr] = fmaf(vh, fast_tanh(qL[rr][h] + kv), acc[rr]);
      }
    }
#pragma unroll
    for (int rr = 0; rr < 4; ++rr) {
      int t = t0 + rr;
      bool valid = (s <= t) && (s < len);
      pbuf[((size_t)b * 512 + t) * 512 + s] = valid ? __expf(acc[rr] + vb - 20.f) : 0.f;
    }
  }
}

// ---------------------------------------------------------------- K5: invl[row] = 1 / sum_s p[row][s]
__global__ __launch_bounds__(256) void k_rowinv(const float* __restrict__ pbuf, float* __restrict__ invl) {
  int row = blockIdx.x * 4 + (threadIdx.x >> 6);
  int lane = threadIdx.x & 63;
  const float* pr = pbuf + (size_t)row * 512;
  float s = 0.f;
#pragma unroll
  for (int i = 0; i < 8; ++i) s += pr[lane + i * 64];
#pragma unroll
  for (int m = 1; m < 64; m <<= 1) s += __shfl_xor(s, m);
  if (lane == 0) invl[row] = 1.0f / s;
}

// ---------------------------------------------------------------- K5b: feats[:, 0:512] = bf16(out)
__global__ __launch_bounds__(256) void k_cvt_out_feats(const float* __restrict__ out,
                                                       unsigned short* __restrict__ feats) {
  int i = (blockIdx.x * 256 + threadIdx.x) * 8;
  int m = i >> 9, c = i & 511;
  float4 a = *(const float4*)(out + i);
  float4 b = *(const float4*)(out + i + 4);
  short8 v;
  v[0] = bf16r(a.x); v[1] = bf16r(a.y); v[2] = bf16r(a.z); v[3] = bf16r(a.w);
  v[4] = bf16r(b.x); v[5] = bf16r(b.y); v[6] = bf16r(b.z); v[7] = bf16r(b.w);
  *(short8*)(feats + (size_t)m * 1024 + c) = v;
}

// ---------------------------------------------------------------- K6: feats[:, 512:1024] = bf16((p @ out) * invl)
__global__ __launch_bounds__(256) void k_context(const float* __restrict__ pbuf, const float* __restrict__ out,
                                                 const float* __restrict__ invl, unsigned short* __restrict__ feats) {
  __shared__ float Pt[64][128];
  __shared__ float Ot[128][64];
  const int b = blockIdx.z, t0 = blockIdx.y * 64, h0 = blockIdx.x * 64;
  const int tid = threadIdx.x, ty = tid >> 4, tx = tid & 15;
  float acc[4][4] = {};
  for (int sc = 0; sc < 512; sc += 128) {
#pragma unroll
    for (int rr = 0; rr < 8; ++rr) {
      int row = rr * 8 + (tid >> 5);
      int col = (tid & 31) * 4;
      *(float4*)&Pt[row][col] = *(const float4*)&pbuf[((size_t)b * 512 + t0 + row) * 512 + sc + col];
    }
#pragma unroll
    for (int rr = 0; rr < 8; ++rr) {
      int srow = rr * 16 + (tid >> 4);
      int col = (tid & 15) * 4;
      *(float4*)&Ot[srow][col] = *(const float4*)&out[((size_t)b * 512 + sc + srow) * 512 + h0 + col];
    }
    __syncthreads();
    for (int kk = 0; kk < 128; ++kk) {
      float ov[4];
#pragma unroll
      for (int c = 0; c < 4; ++c) ov[c] = Ot[kk][tx * 4 + c];
#pragma unroll
      for (int a = 0; a < 4; ++a) {
        float pv = Pt[ty * 4 + a][kk];
#pragma unroll
        for (int c = 0; c < 4; ++c) acc[a][c] = fmaf(pv, ov[c], acc[a][c]);
      }
    }
    __syncthreads();
  }
#pragma unroll
  for (int a = 0; a < 4; ++a) {
    int t = t0 + ty * 4 + a;
    float il = invl[b * 512 + t];
#pragma unroll
    for (int c = 0; c < 4; ++c) {
      int h = h0 + tx * 4 + c;
      feats[((size_t)b * 512 + t) * 1024 + 512 + h] = (unsigned short)bf16r(acc[a][c] * il);
    }
  }
}

// ---------------------------------------------------------------- K7: logits = feats @ fc_W^T + fc_b (bf16 MFMA)
__global__ __launch_bounds__(256) void k_logits(const unsigned short* __restrict__ A,
                                                const unsigned short* __restrict__ Bw,
                                                const float* __restrict__ bias, float* __restrict__ C) {
  __shared__ unsigned short As[128 * 64];
  __shared__ unsigned short Bs[128 * 64];
  const int tid = threadIdx.x;
  const int wave = tid >> 6, lane = tid & 63;
  const int m0 = blockIdx.x * 128, n0 = blockIdx.y * 128;
  const int wm = (wave >> 1) * 64, wn = (wave & 1) * 64;
  const int lo16 = lane & 15, oct = lane >> 4;
  f32x4 acc[4][4] = {};
  for (int kt = 0; kt < 1024; kt += 64) {
#pragma unroll
    for (int i = 0; i < 4; ++i) {
      int ci = wave * 4 + i;
      int mrow = ci * 8 + (lane >> 3);
      int k8 = (lane & 7) * 8;
      glds16(&A[(size_t)(m0 + mrow) * 1024 + kt + k8], &As[ci * 512]);
      glds16(&Bw[(size_t)(n0 + mrow) * 1024 + kt + k8], &Bs[ci * 512]);
    }
    __syncthreads();
#pragma unroll
    for (int kk = 0; kk < 2; ++kk) {
      short8 af[4], bf[4];
#pragma unroll
      for (int i = 0; i < 4; ++i)
        af[i] = *(const short8*)&As[(wm + i * 16 + lo16) * 64 + kk * 32 + oct * 8];
#pragma unroll
      for (int jn = 0; jn < 4; ++jn)
        bf[jn] = *(const short8*)&Bs[(wn + jn * 16 + lo16) * 64 + kk * 32 + oct * 8];
#pragma unroll
      for (int i = 0; i < 4; ++i)
#pragma unroll
        for (int jn = 0; jn < 4; ++jn)
          acc[i][jn] = __builtin_amdgcn_mfma_f32_16x16x32_bf16(af[i], bf[jn], acc[i][jn], 0, 0, 0);
    }
    __syncthreads();
  }
#pragma unroll
  for (int jn = 0; jn < 4; ++jn) {
    int nn = n0 + wn + jn * 16 + lo16;
    float bv = bias[nn];
#pragma unroll
    for (int i = 0; i < 4; ++i) {
      int mbase = m0 + wm + i * 16 + oct * 4;
#pragma unroll
      for (int rr = 0; rr < 4; ++rr)
        C[(size_t)(mbase + rr) * 32000 + nn] = acc[i][jn][rr] + bv;
    }
  }
}

// ---------------------------------------------------------------- launch
extern "C" void kernel_launch(void* const* d_in, const int* in_sizes, int n_in,
                              void* d_out, int out_size, void* d_ws, size_t ws_size,
                              hipStream_t stream) {
  const int* x = (const int*)d_in[0];
  const int* lengths = (const int*)d_in[1];
  const float* embed = (const float*)d_in[2];
  const float* W_ih = (const float*)d_in[3];
  const float* W_hh = (const float*)d_in[4];
  const float* b_ih = (const float*)d_in[5];
  const float* b_hh = (const float*)d_in[6];
  const float* attn_W = (const float*)d_in[7];
  const float* attn_b = (const float*)d_in[8];
  const float* attn_v = (const float*)d_in[9];
  const float* attn_v_b = (const float*)d_in[10];
  const float* fc_W = (const float*)d_in[11];
  const float* fc_b = (const float*)d_in[12];
  float* logits = (float*)d_out;

  char* ws = (char*)d_ws;
  const size_t MB8 = 8388608;
  float* xin  = (float*)(ws);
  float* outp = (float*)(ws + 1 * MB8);
  float* q    = (float*)(ws + 2 * MB8);
  float* kT   = (float*)(ws + 3 * MB8);
  float* pbuf = (float*)(ws + 4 * MB8);
  float* invl = (float*)(ws + 5 * MB8);
  unsigned short* feats = (unsigned short*)(ws + 5 * MB8 + 16384);
  unsigned short* fcWb  = (unsigned short*)(ws + 6 * MB8 + 16384);
  // mbox aliases pbuf: [8 dst][16 slots][16 KB] = 2 MB. Dead once k_rnn
  // completes; k_scores then fully overwrites pbuf.
  unsigned long long* mbox = (unsigned long long*)pbuf;

  hipMemsetAsync(mbox, 0xFF, 8 * 16 * 16384, stream);  // sentinel all ring slots
  for (int d = 0; d < 8; ++d)                          // slot 0 of each mailbox = h_0 = 0
    hipMemsetAsync((char*)mbox + (size_t)d * 16 * 16384, 0x00, 16384, stream);
  k_cvt_bf16<<<16000, 256, 0, stream>>>(fc_W, fcWb, 32768000);
  k_xin<<<dim3(64, 8), 256, 0, stream>>>(x, embed, W_ih, b_ih, xin);
  k_rnn<<<8, 512, 0, stream>>>(xin, W_hh, b_hh, lengths, mbox, outp);
  k_qk<0><<<dim3(64, 8), 256, 0, stream>>>(outp, attn_W, attn_b, q);
  k_qk<1><<<dim3(64, 8), 256, 0, stream>>>(outp, attn_W, attn_b, kT);
  k_scores<<<dim3(8, 128), 256, 0, stream>>>(q, kT, attn_v, attn_v_b, lengths, pbuf);
  k_rowinv<<<1024, 256, 0, stream>>>(pbuf, invl);
  k_cvt_out_feats<<<1024, 256, 0, stream>>>(outp, feats);
  k_context<<<dim3(8, 8, 8), 256, 0, stream>>>(pbuf, outp, invl, feats);
  k_logits<<<dim3(32, 250), 256, 0, stream>>>(feats, fcWb, fc_b, logits);
}